// Round 3
// baseline (1319.902 us; speedup 1.0000x reference)
//
#include <hip/hip_runtime.h>
#include <hip/hip_bf16.h>

// ---------------- common helpers ----------------
typedef unsigned short u16;
typedef __attribute__((ext_vector_type(8))) short bf16x8;
typedef __attribute__((ext_vector_type(4))) float floatx4;

__device__ __forceinline__ u16 f2b(float f) {
    union { float f; unsigned int u; } a; a.f = f;
    unsigned int u = a.u;
    unsigned int r = (u + 0x7fffu + ((u >> 16) & 1u)) >> 16; // RNE bf16
    return (u16)r;
}

// async global->LDS, 16B per lane (global_load_lds_dwordx4)
__device__ __forceinline__ void gload_lds16(const void* g, void* l) {
    auto gp = (const __attribute__((address_space(1))) unsigned int*)g;
    auto lp = (__attribute__((address_space(3))) unsigned int*)l;
    __builtin_amdgcn_global_load_lds(gp, lp, 16, 0, 0);
}

// ---------------- LayerNorm (ddof=1), writes fp32 + bf16 ----------------
__global__ __launch_bounds__(256) void k_ln(const float* __restrict__ x,
                                            const float* __restrict__ g,
                                            const float* __restrict__ be,
                                            float* __restrict__ yf,
                                            u16* __restrict__ yb) {
    const int row = blockIdx.x;
    const int t = threadIdx.x;
    const float4 xv = ((const float4*)(x + (size_t)row * 1024))[t];
    float s  = xv.x + xv.y + xv.z + xv.w;
    float ss = xv.x * xv.x + xv.y * xv.y + xv.z * xv.z + xv.w * xv.w;
    for (int m = 1; m < 64; m <<= 1) {
        s  += __shfl_xor(s, m);
        ss += __shfl_xor(ss, m);
    }
    __shared__ float sm[8];
    const int wave = t >> 6, lane = t & 63;
    if (lane == 0) { sm[wave] = s; sm[4 + wave] = ss; }
    __syncthreads();
    s  = sm[0] + sm[1] + sm[2] + sm[3];
    ss = sm[4] + sm[5] + sm[6] + sm[7];
    const float mean = s * (1.0f / 1024.0f);
    const float var  = (ss - 1024.0f * mean * mean) * (1.0f / 1023.0f); // ddof=1
    const float rstd = rsqrtf(var + 1e-5f);
    const float4 gv = ((const float4*)g)[t];
    const float4 bv = ((const float4*)be)[t];
    float4 y;
    y.x = (xv.x - mean) * rstd * gv.x + bv.x;
    y.y = (xv.y - mean) * rstd * gv.y + bv.y;
    y.z = (xv.z - mean) * rstd * gv.z + bv.z;
    y.w = (xv.w - mean) * rstd * gv.w + bv.w;
    ((float4*)(yf + (size_t)row * 1024))[t] = y;
    uint2 pk;
    pk.x = (unsigned int)f2b(y.x) | ((unsigned int)f2b(y.y) << 16);
    pk.y = (unsigned int)f2b(y.z) | ((unsigned int)f2b(y.w) << 16);
    *(uint2*)(yb + (size_t)row * 1024 + t * 4) = pk;
}

// ---------------- weight transpose + convert: W(KxN) fp32 -> Wt(NxK) bf16 ----------------
__global__ __launch_bounds__(256) void k_tconv(const float* __restrict__ W,
                                               u16* __restrict__ Wt,
                                               int K, int N) {
    __shared__ float tile[32][33];
    const int n0 = blockIdx.x * 32, k0 = blockIdx.y * 32;
    const int tx = threadIdx.x, ty = threadIdx.y; // 32 x 8
    for (int i = 0; i < 4; i++) {
        const int kr = ty + i * 8;
        tile[kr][tx] = W[(size_t)(k0 + kr) * N + n0 + tx];
    }
    __syncthreads();
    for (int i = 0; i < 4; i++) {
        const int nr = ty + i * 8;
        Wt[(size_t)(n0 + nr) * K + k0 + tx] = f2b(tile[tx][nr]);
    }
}

// ---------------- per-head V transpose: v[b*T][D] -> vt[b][h][d][t] (bf16) ----------------
// grid (16 t-tiles, 16 h, 8 b), 256 threads; 64x64 tile via LDS, coalesced both sides
__global__ __launch_bounds__(256) void k_vtrans(const u16* __restrict__ v,
                                                u16* __restrict__ vt) {
    __shared__ u16 tile[64][80]; // row stride 160B: 16B-aligned, banks rotate by 8
    const int t = threadIdx.x;
    const int t0 = blockIdx.x * 64, hh = blockIdx.y, bb = blockIdx.z;
    const int r = t >> 2, c0 = (t & 3) * 16;
    const u16* src = v + ((size_t)(bb * 1024 + t0 + r)) * 1024 + hh * 64 + c0;
    *(uint4*)&tile[r][c0]     = *(const uint4*)src;
    *(uint4*)&tile[r][c0 + 8] = *(const uint4*)(src + 8);
    __syncthreads();
    // out: row d = t>>2, t-chunk c0: vt[((bb*16+hh)*64+d)*1024 + t0 + c0 .. +15]
    const int d = t >> 2;
    u16* dst = vt + (((size_t)(bb * 16 + hh) * 64 + d)) * 1024 + t0 + c0;
    union { u16 s[8]; uint4 v4; } pk;
    for (int j = 0; j < 8; j++) pk.s[j] = tile[c0 + j][d];
    *(uint4*)dst = pk.v4;
    for (int j = 0; j < 8; j++) pk.s[j] = tile[c0 + 8 + j][d];
    *(uint4*)(dst + 8) = pk.v4;
}

// ---------------- bf16 MFMA GEMM: C = A(MxK) @ Bt(NxK)^T + bias ----------------
// 128x128 tile, BK=32, 256 threads (4 waves, each 64x64 = 4x4 frags of 16x16x32)
// staging via global_load_lds width=16 (m97 ladder step)
template <bool GELU, bool RESID, bool WF32, bool WBF16>
__global__ __launch_bounds__(256) void k_gemm(const u16* __restrict__ A,
                                              const u16* __restrict__ Bt,
                                              const float* __restrict__ bias,
                                              const float* __restrict__ resid,
                                              float* __restrict__ outF,
                                              u16* __restrict__ outB,
                                              int M, int N, int K) {
    __shared__ u16 As[128 * 32];
    __shared__ u16 Bs[128 * 32];
    const int t = threadIdx.x;
    const int m0 = blockIdx.y * 128, n0 = blockIdx.x * 128;
    const int lane = t & 63, wave = t >> 6;
    const int wm = (wave >> 1) * 64, wn = (wave & 1) * 64;
    const int r16 = lane & 15, quad = lane >> 4;

    floatx4 acc[4][4];
    const floatx4 zero = {0.0f, 0.0f, 0.0f, 0.0f};
    for (int i = 0; i < 4; i++)
        for (int j = 0; j < 4; j++) acc[i][j] = zero;

    // staging: tile = 128 rows x 64B = 512 x 16B chunks; 2 chunks/thread.
    // LDS dst offset = chunk*16B (lane-contiguous: wave-uniform base + lane*16)
    const int c0 = t, c1 = t + 256;
    const int r0 = c0 >> 2, f0 = c0 & 3;
    const int r1 = c1 >> 2, f1 = c1 & 3;
    const u16* pa0 = A  + (size_t)(m0 + r0) * K + f0 * 8;
    const u16* pb0 = Bt + (size_t)(n0 + r0) * K + f0 * 8;
    const u16* pa1 = A  + (size_t)(m0 + r1) * K + f1 * 8;
    const u16* pb1 = Bt + (size_t)(n0 + r1) * K + f1 * 8;

    for (int kk = 0; kk < K; kk += 32) {
        gload_lds16(pa0 + kk, As + c0 * 8);
        gload_lds16(pb0 + kk, Bs + c0 * 8);
        gload_lds16(pa1 + kk, As + c1 * 8);
        gload_lds16(pb1 + kk, Bs + c1 * 8);
        __syncthreads(); // drains vmcnt -> LDS valid

        bf16x8 af[4], bfr[4];
        for (int i = 0; i < 4; i++)
            af[i] = *(const bf16x8*)(As + (wm + i * 16 + r16) * 32 + quad * 8);
        for (int i = 0; i < 4; i++)
            bfr[i] = *(const bf16x8*)(Bs + (wn + i * 16 + r16) * 32 + quad * 8);
        for (int mi = 0; mi < 4; mi++)
            for (int ni = 0; ni < 4; ni++)
                acc[mi][ni] = __builtin_amdgcn_mfma_f32_16x16x32_bf16(af[mi], bfr[ni], acc[mi][ni], 0, 0, 0);
        __syncthreads();
    }

    // epilogue: C/D layout col = lane&15, row = quad*4 + reg
    for (int mi = 0; mi < 4; mi++)
        for (int ni = 0; ni < 4; ni++) {
            const int gcol = n0 + wn + ni * 16 + r16;
            const float bv = bias[gcol];
            for (int r = 0; r < 4; r++) {
                const int grow = m0 + wm + mi * 16 + quad * 4 + r;
                float v = acc[mi][ni][r] + bv;
                if (GELU) v = 0.5f * v * (1.0f + erff(v * 0.70710678118654752f));
                const size_t o = (size_t)grow * N + gcol;
                if (RESID) v += resid[o];
                if (WF32) outF[o] = v;
                if (WBF16) outB[o] = f2b(v);
            }
        }
}

// ---------------- bf16 MFMA flash attention ----------------
// grid: B*H*(T/64)=2048 blocks x 256 threads. Block = one (b,h), 64 q rows.
// q,k: bf16 [b*T][1024] (head h at cols h*64..). vt: bf16 [b][h][64][1024].
__global__ __launch_bounds__(256) void k_attn_mfma(const u16* __restrict__ q,
                                                   const u16* __restrict__ k,
                                                   const u16* __restrict__ vt,
                                                   u16* __restrict__ ctx) {
    __shared__ u16 Qs[2][64][32];
    __shared__ u16 Ks[2][64][32];
    __shared__ u16 Vs[2][64][32]; // Vs[p][d][s'], s = p*32+s'
    __shared__ u16 Ps[2][64][32]; // Ps[p][qrow][s']
    const int t = threadIdx.x;
    const int lane = t & 63, wave = t >> 6;
    const int r16 = lane & 15, quad = lane >> 4;
    const int wq = wave * 16;
    const int bx = blockIdx.x;
    const int qt = bx & 15, hh = (bx >> 4) & 15, bb = bx >> 8;
    const size_t qk_base = ((size_t)bb * 1024) * 1024 + hh * 64;
    const size_t vt_base = ((size_t)(bb * 16 + hh) * 64) * 1024;
    const int q0 = qt * 64;

    const int srow = t >> 2, ch = t & 3;
    const int pnl = ch >> 1, soff = (ch & 1) * 16;
    {
        const u16* gp = q + qk_base + (size_t)(q0 + srow) * 1024 + ch * 16;
        *(uint4*)&Qs[pnl][srow][soff]     = *(const uint4*)gp;
        *(uint4*)&Qs[pnl][srow][soff + 8] = *(const uint4*)(gp + 8);
    }

    float m_i[4], l_i[4];
    floatx4 acc_o[4];
    const floatx4 zero = {0.0f, 0.0f, 0.0f, 0.0f};
    for (int r = 0; r < 4; r++) { m_i[r] = -INFINITY; l_i[r] = 0.0f; }
    for (int ni = 0; ni < 4; ni++) acc_o[ni] = zero;

    for (int st = 0; st < 16; st++) {
        __syncthreads();
        const int s0 = st * 64;
        {
            const u16* gk = k + qk_base + (size_t)(s0 + srow) * 1024 + ch * 16;
            *(uint4*)&Ks[pnl][srow][soff]     = *(const uint4*)gk;
            *(uint4*)&Ks[pnl][srow][soff + 8] = *(const uint4*)(gk + 8);
            const u16* gv = vt + vt_base + (size_t)srow * 1024 + s0 + ch * 16;
            *(uint4*)&Vs[pnl][srow][soff]     = *(const uint4*)gv;
            *(uint4*)&Vs[pnl][srow][soff + 8] = *(const uint4*)(gv + 8);
        }
        __syncthreads();

        floatx4 accs[4];
        for (int ni = 0; ni < 4; ni++) accs[ni] = zero;
        for (int ks = 0; ks < 2; ks++) {
            const bf16x8 af = *(const bf16x8*)&Qs[ks][wq + r16][quad * 8];
            for (int ni = 0; ni < 4; ni++) {
                const bf16x8 bf = *(const bf16x8*)&Ks[ks][ni * 16 + r16][quad * 8];
                accs[ni] = __builtin_amdgcn_mfma_f32_16x16x32_bf16(af, bf, accs[ni], 0, 0, 0);
            }
        }

        for (int r = 0; r < 4; r++) {
            float sv[4];
            float mx = -INFINITY;
            for (int ni = 0; ni < 4; ni++) {
                sv[ni] = accs[ni][r] * 0.125f;
                mx = fmaxf(mx, sv[ni]);
            }
            for (int m = 1; m < 16; m <<= 1) mx = fmaxf(mx, __shfl_xor(mx, m));
            const float mn = fmaxf(m_i[r], mx);
            const float al = __expf(m_i[r] - mn);
            float ps = 0.0f;
            u16 pb[4];
            for (int ni = 0; ni < 4; ni++) {
                const float p = __expf(sv[ni] - mn);
                ps += p;
                pb[ni] = f2b(p);
            }
            for (int m = 1; m < 16; m <<= 1) ps += __shfl_xor(ps, m);
            l_i[r] = l_i[r] * al + ps;
            m_i[r] = mn;
            for (int ni = 0; ni < 4; ni++) acc_o[ni][r] *= al;
            const int prow = wq + quad * 4 + r;
            for (int ni = 0; ni < 4; ni++)
                Ps[ni >> 1][prow][(ni & 1) * 16 + r16] = pb[ni];
        }
        // P written & read by the same wave -> no barrier needed

        for (int ks = 0; ks < 2; ks++) {
            const bf16x8 af = *(const bf16x8*)&Ps[ks][wq + r16][quad * 8];
            for (int ni = 0; ni < 4; ni++) {
                const bf16x8 bf = *(const bf16x8*)&Vs[ks][ni * 16 + r16][quad * 8];
                acc_o[ni] = __builtin_amdgcn_mfma_f32_16x16x32_bf16(af, bf, acc_o[ni], 0, 0, 0);
            }
        }
    }

    for (int r = 0; r < 4; r++) {
        const float inv = 1.0f / l_i[r];
        const size_t rowoff = qk_base + (size_t)(q0 + wq + quad * 4 + r) * 1024;
        for (int ni = 0; ni < 4; ni++)
            ctx[rowoff + ni * 16 + r16] = f2b(acc_o[ni][r] * inv);
    }
}

// ---------------- launcher ----------------
extern "C" void kernel_launch(void* const* d_in, const int* in_sizes, int n_in,
                              void* d_out, int out_size, void* d_ws, size_t ws_size,
                              hipStream_t stream) {
    const float* x   = (const float*)d_in[0];
    const float* Wq  = (const float*)d_in[1];
    const float* bq  = (const float*)d_in[2];
    const float* Wk  = (const float*)d_in[3];
    const float* bk  = (const float*)d_in[4];
    const float* Wv  = (const float*)d_in[5];
    const float* bv  = (const float*)d_in[6];
    const float* Wo  = (const float*)d_in[7];
    const float* bo  = (const float*)d_in[8];
    const float* W1  = (const float*)d_in[9];
    const float* b1  = (const float*)d_in[10];
    const float* W2  = (const float*)d_in[11];
    const float* b2  = (const float*)d_in[12];
    const float* g1  = (const float*)d_in[13];
    const float* be1 = (const float*)d_in[14];
    const float* g2  = (const float*)d_in[15];
    const float* be2 = (const float*)d_in[16];
    float* out = (float*)d_out;

    const size_t MB = 1ull << 20;
    char* ws = (char*)d_ws;
    // layout (184 MB):
    float* h_f   = (float*)(ws + 0);          // 32MB fp32 h (live to Wo resid)
    u16*   h_b   = (u16*)(ws + 32 * MB);      // 16MB bf16 h; reused as ctx after QKV
    u16*   q_b   = (u16*)(ws + 48 * MB);      // 16MB
    u16*   k_b   = (u16*)(ws + 64 * MB);      // 16MB
    u16*   v_b   = (u16*)(ws + 80 * MB);      // 16MB (row-major V)
    u16*   vt_b  = (u16*)(ws + 96 * MB);      // 16MB (per-head transposed)
    u16*   g_b   = (u16*)(ws + 48 * MB);      // 64MB gelu acts; reuses q/k/v/vt after attention
    float* hres  = (float*)(ws + 112 * MB);   // 32MB, LN2 in-place
    u16*   h2_b  = (u16*)(ws + 144 * MB);     // 16MB
    u16*   wq_t  = (u16*)(ws + 160 * MB);     // 2MB each
    u16*   wk_t  = (u16*)(ws + 162 * MB);
    u16*   wv_t  = (u16*)(ws + 164 * MB);
    u16*   wo_t  = (u16*)(ws + 166 * MB);
    u16*   w1_t  = (u16*)(ws + 168 * MB);     // 8MB
    u16*   w2_t  = (u16*)(ws + 176 * MB);     // 8MB -> ends at 184MB
    u16*   ctx_b = h_b;

    const int M = 8192, D = 1024, FF = 4096;
    const dim3 tb(32, 8);

    // weight prep
    k_tconv<<<dim3(32, 32), tb, 0, stream>>>(Wq, wq_t, D, D);
    k_tconv<<<dim3(32, 32), tb, 0, stream>>>(Wk, wk_t, D, D);
    k_tconv<<<dim3(32, 32), tb, 0, stream>>>(Wv, wv_t, D, D);
    k_tconv<<<dim3(32, 32), tb, 0, stream>>>(Wo, wo_t, D, D);
    k_tconv<<<dim3(128, 32), tb, 0, stream>>>(W1, w1_t, D, FF);
    k_tconv<<<dim3(32, 128), tb, 0, stream>>>(W2, w2_t, FF, D);

    // LN1
    k_ln<<<M, 256, 0, stream>>>(x, g1, be1, h_f, h_b);

    // QKV GEMMs -> bf16 row-major
    k_gemm<false, false, false, true><<<dim3(8, 64), 256, 0, stream>>>(h_b, wq_t, bq, nullptr, nullptr, q_b, M, D, D);
    k_gemm<false, false, false, true><<<dim3(8, 64), 256, 0, stream>>>(h_b, wk_t, bk, nullptr, nullptr, k_b, M, D, D);
    k_gemm<false, false, false, true><<<dim3(8, 64), 256, 0, stream>>>(h_b, wv_t, bv, nullptr, nullptr, v_b, M, D, D);

    // per-head V transpose (coalesced)
    k_vtrans<<<dim3(16, 16, 8), 256, 0, stream>>>(v_b, vt_b);

    // MFMA flash attention -> ctx bf16
    k_attn_mfma<<<2048, 256, 0, stream>>>(q_b, k_b, vt_b, ctx_b);

    // Wo + residual(h)
    k_gemm<false, true, true, false><<<dim3(8, 64), 256, 0, stream>>>(ctx_b, wo_t, bo, h_f, hres, nullptr, M, D, D);

    // LN2 (in-place fp32 + bf16)
    k_ln<<<M, 256, 0, stream>>>(hres, g2, be2, hres, h2_b);

    // FFN1 + exact GELU
    k_gemm<true, false, false, true><<<dim3(32, 64), 256, 0, stream>>>(h2_b, w1_t, b1, nullptr, nullptr, g_b, M, FF, D);

    // FFN2 + residual(h2)
    k_gemm<false, true, true, false><<<dim3(8, 64), 256, 0, stream>>>(g_b, w2_t, b2, hres, out, nullptr, M, D, FF);
}

// Round 4
// 1265.850 us; speedup vs baseline: 1.0427x; 1.0427x over previous
//
#include <hip/hip_runtime.h>
#include <hip/hip_bf16.h>

// ---------------- common helpers ----------------
typedef unsigned short u16;
typedef __attribute__((ext_vector_type(8))) short bf16x8;
typedef __attribute__((ext_vector_type(4))) float floatx4;

__device__ __forceinline__ u16 f2b(float f) {
    union { float f; unsigned int u; } a; a.f = f;
    unsigned int u = a.u;
    unsigned int r = (u + 0x7fffu + ((u >> 16) & 1u)) >> 16; // RNE bf16
    return (u16)r;
}

// async global->LDS, 16B per lane (global_load_lds_dwordx4)
__device__ __forceinline__ void gload_lds16(const void* g, void* l) {
    auto gp = (const __attribute__((address_space(1))) unsigned int*)g;
    auto lp = (__attribute__((address_space(3))) unsigned int*)l;
    __builtin_amdgcn_global_load_lds(gp, lp, 16, 0, 0);
}

// ---------------- LayerNorm (ddof=1), writes fp32 + bf16 ----------------
__global__ __launch_bounds__(256) void k_ln(const float* __restrict__ x,
                                            const float* __restrict__ g,
                                            const float* __restrict__ be,
                                            float* __restrict__ yf,
                                            u16* __restrict__ yb) {
    const int row = blockIdx.x;
    const int t = threadIdx.x;
    const float4 xv = ((const float4*)(x + (size_t)row * 1024))[t];
    float s  = xv.x + xv.y + xv.z + xv.w;
    float ss = xv.x * xv.x + xv.y * xv.y + xv.z * xv.z + xv.w * xv.w;
    for (int m = 1; m < 64; m <<= 1) {
        s  += __shfl_xor(s, m);
        ss += __shfl_xor(ss, m);
    }
    __shared__ float sm[8];
    const int wave = t >> 6, lane = t & 63;
    if (lane == 0) { sm[wave] = s; sm[4 + wave] = ss; }
    __syncthreads();
    s  = sm[0] + sm[1] + sm[2] + sm[3];
    ss = sm[4] + sm[5] + sm[6] + sm[7];
    const float mean = s * (1.0f / 1024.0f);
    const float var  = (ss - 1024.0f * mean * mean) * (1.0f / 1023.0f); // ddof=1
    const float rstd = rsqrtf(var + 1e-5f);
    const float4 gv = ((const float4*)g)[t];
    const float4 bv = ((const float4*)be)[t];
    float4 y;
    y.x = (xv.x - mean) * rstd * gv.x + bv.x;
    y.y = (xv.y - mean) * rstd * gv.y + bv.y;
    y.z = (xv.z - mean) * rstd * gv.z + bv.z;
    y.w = (xv.w - mean) * rstd * gv.w + bv.w;
    ((float4*)(yf + (size_t)row * 1024))[t] = y;
    uint2 pk;
    pk.x = (unsigned int)f2b(y.x) | ((unsigned int)f2b(y.y) << 16);
    pk.y = (unsigned int)f2b(y.z) | ((unsigned int)f2b(y.w) << 16);
    *(uint2*)(yb + (size_t)row * 1024 + t * 4) = pk;
}

// ---------------- weight transpose + convert: W(KxN) fp32 -> Wt(NxK) bf16 ----------------
__global__ __launch_bounds__(256) void k_tconv(const float* __restrict__ W,
                                               u16* __restrict__ Wt,
                                               int K, int N) {
    __shared__ float tile[32][33];
    const int n0 = blockIdx.x * 32, k0 = blockIdx.y * 32;
    const int tx = threadIdx.x, ty = threadIdx.y; // 32 x 8
    for (int i = 0; i < 4; i++) {
        const int kr = ty + i * 8;
        tile[kr][tx] = W[(size_t)(k0 + kr) * N + n0 + tx];
    }
    __syncthreads();
    for (int i = 0; i < 4; i++) {
        const int nr = ty + i * 8;
        Wt[(size_t)(n0 + nr) * K + k0 + tx] = f2b(tile[tx][nr]);
    }
}

// ---------------- per-head V transpose: v[b*T][D] -> vt[b][h][d][t] (bf16) ----------------
__global__ __launch_bounds__(256) void k_vtrans(const u16* __restrict__ v,
                                                u16* __restrict__ vt) {
    __shared__ u16 tile[64][80];
    const int t = threadIdx.x;
    const int t0 = blockIdx.x * 64, hh = blockIdx.y, bb = blockIdx.z;
    const int r = t >> 2, c0 = (t & 3) * 16;
    const u16* src = v + ((size_t)(bb * 1024 + t0 + r)) * 1024 + hh * 64 + c0;
    *(uint4*)&tile[r][c0]     = *(const uint4*)src;
    *(uint4*)&tile[r][c0 + 8] = *(const uint4*)(src + 8);
    __syncthreads();
    const int d = t >> 2;
    u16* dst = vt + (((size_t)(bb * 16 + hh) * 64 + d)) * 1024 + t0 + c0;
    union { u16 s[8]; uint4 v4; } pk;
    for (int j = 0; j < 8; j++) pk.s[j] = tile[c0 + j][d];
    *(uint4*)dst = pk.v4;
    for (int j = 0; j < 8; j++) pk.s[j] = tile[c0 + 8 + j][d];
    *(uint4*)(dst + 8) = pk.v4;
}

// ---------------- bf16 MFMA GEMM: C = A(MxK) @ Bt(NxK)^T + bias ----------------
// 128x128 tile, BK=32, 256 threads (4 waves, each 64x64 = 4x4 frags of 16x16x32)
// QKV: N=3072 fused; route output cols [0,1024)->q, [1024,2048)->k, [2048,3072)->v,
//      each a row-major [8192][1024] bf16 region contiguous in outB; bias by section.
template <bool GELU, bool RESID, bool WF32, bool WBF16, bool QKV = false>
__global__ __launch_bounds__(256) void k_gemm(const u16* __restrict__ A,
                                              const u16* __restrict__ Bt,
                                              const float* __restrict__ bias,
                                              const float* __restrict__ resid,
                                              float* __restrict__ outF,
                                              u16* __restrict__ outB,
                                              int M, int N, int K,
                                              const float* __restrict__ bias2 = nullptr,
                                              const float* __restrict__ bias3 = nullptr) {
    __shared__ u16 As[128 * 32];
    __shared__ u16 Bs[128 * 32];
    const int t = threadIdx.x;
    const int m0 = blockIdx.y * 128, n0 = blockIdx.x * 128;
    const int lane = t & 63, wave = t >> 6;
    const int wm = (wave >> 1) * 64, wn = (wave & 1) * 64;
    const int r16 = lane & 15, quad = lane >> 4;

    floatx4 acc[4][4];
    const floatx4 zero = {0.0f, 0.0f, 0.0f, 0.0f};
    for (int i = 0; i < 4; i++)
        for (int j = 0; j < 4; j++) acc[i][j] = zero;

    const int c0 = t, c1 = t + 256;
    const int r0 = c0 >> 2, f0 = c0 & 3;
    const int r1 = c1 >> 2, f1 = c1 & 3;
    const u16* pa0 = A  + (size_t)(m0 + r0) * K + f0 * 8;
    const u16* pb0 = Bt + (size_t)(n0 + r0) * K + f0 * 8;
    const u16* pa1 = A  + (size_t)(m0 + r1) * K + f1 * 8;
    const u16* pb1 = Bt + (size_t)(n0 + r1) * K + f1 * 8;

    for (int kk = 0; kk < K; kk += 32) {
        gload_lds16(pa0 + kk, As + c0 * 8);
        gload_lds16(pb0 + kk, Bs + c0 * 8);
        gload_lds16(pa1 + kk, As + c1 * 8);
        gload_lds16(pb1 + kk, Bs + c1 * 8);
        __syncthreads();

        bf16x8 af[4], bfr[4];
        for (int i = 0; i < 4; i++)
            af[i] = *(const bf16x8*)(As + (wm + i * 16 + r16) * 32 + quad * 8);
        for (int i = 0; i < 4; i++)
            bfr[i] = *(const bf16x8*)(Bs + (wn + i * 16 + r16) * 32 + quad * 8);
        for (int mi = 0; mi < 4; mi++)
            for (int ni = 0; ni < 4; ni++)
                acc[mi][ni] = __builtin_amdgcn_mfma_f32_16x16x32_bf16(af[mi], bfr[ni], acc[mi][ni], 0, 0, 0);
        __syncthreads();
    }

    // epilogue: C/D layout col = lane&15, row = quad*4 + reg
    const int sect = QKV ? (n0 >> 10) : 0; // block lies fully in one section
    const float* bp = QKV ? (sect == 0 ? bias : (sect == 1 ? bias2 : bias3)) : bias;
    u16* outQ = QKV ? (outB + (size_t)sect * (8192ull * 1024ull)) : outB;
    for (int mi = 0; mi < 4; mi++)
        for (int ni = 0; ni < 4; ni++) {
            const int gcol = n0 + wn + ni * 16 + r16;
            const int coln = QKV ? (gcol & 1023) : gcol;
            const float bv = bp[coln];
            for (int r = 0; r < 4; r++) {
                const int grow = m0 + wm + mi * 16 + quad * 4 + r;
                float v = acc[mi][ni][r] + bv;
                if (GELU) v = 0.5f * v * (1.0f + erff(v * 0.70710678118654752f));
                if (QKV) {
                    outQ[(size_t)grow * 1024 + coln] = f2b(v);
                } else {
                    const size_t o = (size_t)grow * N + gcol;
                    if (RESID) v += resid[o];
                    if (WF32) outF[o] = v;
                    if (WBF16) outB[o] = f2b(v);
                }
            }
        }
}

// ---------------- bf16 MFMA flash attention ----------------
__global__ __launch_bounds__(256) void k_attn_mfma(const u16* __restrict__ q,
                                                   const u16* __restrict__ k,
                                                   const u16* __restrict__ vt,
                                                   u16* __restrict__ ctx) {
    __shared__ u16 Qs[2][64][32];
    __shared__ u16 Ks[2][64][32];
    __shared__ u16 Vs[2][64][32];
    __shared__ u16 Ps[2][64][32];
    const int t = threadIdx.x;
    const int lane = t & 63, wave = t >> 6;
    const int r16 = lane & 15, quad = lane >> 4;
    const int wq = wave * 16;
    const int bx = blockIdx.x;
    const int qt = bx & 15, hh = (bx >> 4) & 15, bb = bx >> 8;
    const size_t qk_base = ((size_t)bb * 1024) * 1024 + hh * 64;
    const size_t vt_base = ((size_t)(bb * 16 + hh) * 64) * 1024;
    const int q0 = qt * 64;

    const int srow = t >> 2, ch = t & 3;
    const int pnl = ch >> 1, soff = (ch & 1) * 16;
    {
        const u16* gp = q + qk_base + (size_t)(q0 + srow) * 1024 + ch * 16;
        *(uint4*)&Qs[pnl][srow][soff]     = *(const uint4*)gp;
        *(uint4*)&Qs[pnl][srow][soff + 8] = *(const uint4*)(gp + 8);
    }

    float m_i[4], l_i[4];
    floatx4 acc_o[4];
    const floatx4 zero = {0.0f, 0.0f, 0.0f, 0.0f};
    for (int r = 0; r < 4; r++) { m_i[r] = -INFINITY; l_i[r] = 0.0f; }
    for (int ni = 0; ni < 4; ni++) acc_o[ni] = zero;

    for (int st = 0; st < 16; st++) {
        __syncthreads();
        const int s0 = st * 64;
        {
            const u16* gk = k + qk_base + (size_t)(s0 + srow) * 1024 + ch * 16;
            *(uint4*)&Ks[pnl][srow][soff]     = *(const uint4*)gk;
            *(uint4*)&Ks[pnl][srow][soff + 8] = *(const uint4*)(gk + 8);
            const u16* gv = vt + vt_base + (size_t)srow * 1024 + s0 + ch * 16;
            *(uint4*)&Vs[pnl][srow][soff]     = *(const uint4*)gv;
            *(uint4*)&Vs[pnl][srow][soff + 8] = *(const uint4*)(gv + 8);
        }
        __syncthreads();

        floatx4 accs[4];
        for (int ni = 0; ni < 4; ni++) accs[ni] = zero;
        for (int ks = 0; ks < 2; ks++) {
            const bf16x8 af = *(const bf16x8*)&Qs[ks][wq + r16][quad * 8];
            for (int ni = 0; ni < 4; ni++) {
                const bf16x8 bf = *(const bf16x8*)&Ks[ks][ni * 16 + r16][quad * 8];
                accs[ni] = __builtin_amdgcn_mfma_f32_16x16x32_bf16(af, bf, accs[ni], 0, 0, 0);
            }
        }

        for (int r = 0; r < 4; r++) {
            float sv[4];
            float mx = -INFINITY;
            for (int ni = 0; ni < 4; ni++) {
                sv[ni] = accs[ni][r] * 0.125f;
                mx = fmaxf(mx, sv[ni]);
            }
            for (int m = 1; m < 16; m <<= 1) mx = fmaxf(mx, __shfl_xor(mx, m));
            const float mn = fmaxf(m_i[r], mx);
            const float al = __expf(m_i[r] - mn);
            float ps = 0.0f;
            u16 pb[4];
            for (int ni = 0; ni < 4; ni++) {
                const float p = __expf(sv[ni] - mn);
                ps += p;
                pb[ni] = f2b(p);
            }
            for (int m = 1; m < 16; m <<= 1) ps += __shfl_xor(ps, m);
            l_i[r] = l_i[r] * al + ps;
            m_i[r] = mn;
            for (int ni = 0; ni < 4; ni++) acc_o[ni][r] *= al;
            const int prow = wq + quad * 4 + r;
            for (int ni = 0; ni < 4; ni++)
                Ps[ni >> 1][prow][(ni & 1) * 16 + r16] = pb[ni];
        }

        for (int ks = 0; ks < 2; ks++) {
            const bf16x8 af = *(const bf16x8*)&Ps[ks][wq + r16][quad * 8];
            for (int ni = 0; ni < 4; ni++) {
                const bf16x8 bf = *(const bf16x8*)&Vs[ks][ni * 16 + r16][quad * 8];
                acc_o[ni] = __builtin_amdgcn_mfma_f32_16x16x32_bf16(af, bf, acc_o[ni], 0, 0, 0);
            }
        }
    }

    for (int r = 0; r < 4; r++) {
        const float inv = 1.0f / l_i[r];
        const size_t rowoff = qk_base + (size_t)(q0 + wq + quad * 4 + r) * 1024;
        for (int ni = 0; ni < 4; ni++)
            ctx[rowoff + ni * 16 + r16] = f2b(acc_o[ni][r] * inv);
    }
}

// ---------------- launcher ----------------
extern "C" void kernel_launch(void* const* d_in, const int* in_sizes, int n_in,
                              void* d_out, int out_size, void* d_ws, size_t ws_size,
                              hipStream_t stream) {
    const float* x   = (const float*)d_in[0];
    const float* Wq  = (const float*)d_in[1];
    const float* bq  = (const float*)d_in[2];
    const float* Wk  = (const float*)d_in[3];
    const float* bk  = (const float*)d_in[4];
    const float* Wv  = (const float*)d_in[5];
    const float* bv  = (const float*)d_in[6];
    const float* Wo  = (const float*)d_in[7];
    const float* bo  = (const float*)d_in[8];
    const float* W1  = (const float*)d_in[9];
    const float* b1  = (const float*)d_in[10];
    const float* W2  = (const float*)d_in[11];
    const float* b2  = (const float*)d_in[12];
    const float* g1  = (const float*)d_in[13];
    const float* be1 = (const float*)d_in[14];
    const float* g2  = (const float*)d_in[15];
    const float* be2 = (const float*)d_in[16];
    float* out = (float*)d_out;

    const size_t MB = 1ull << 20;
    char* ws = (char*)d_ws;
    // layout (184 MB):
    float* h_f    = (float*)(ws + 0);          // 32MB fp32 h (live to Wo resid)
    u16*   h_b    = (u16*)(ws + 32 * MB);      // 16MB bf16 h; reused as ctx after QKV
    u16*   qkv_b  = (u16*)(ws + 48 * MB);      // 48MB: q|k|v each [8192][1024] bf16
    u16*   q_b    = qkv_b;
    u16*   k_b    = (u16*)(ws + 64 * MB);
    u16*   v_b    = (u16*)(ws + 80 * MB);
    u16*   vt_b   = (u16*)(ws + 96 * MB);      // 16MB per-head transposed V
    u16*   g_b    = (u16*)(ws + 48 * MB);      // 64MB gelu acts; reuses qkv/vt after attn
    float* hres   = (float*)(ws + 112 * MB);   // 32MB, LN2 in-place
    u16*   h2_b   = (u16*)(ws + 144 * MB);     // 16MB
    u16*   wqkv_t = (u16*)(ws + 160 * MB);     // 6MB: q|k|v weights, [3072][1024] bf16
    u16*   wo_t   = (u16*)(ws + 166 * MB);     // 2MB
    u16*   w1_t   = (u16*)(ws + 168 * MB);     // 8MB
    u16*   w2_t   = (u16*)(ws + 176 * MB);     // 8MB -> ends 184MB
    u16*   ctx_b  = h_b;

    const int M = 8192, D = 1024, FF = 4096;
    const dim3 tb(32, 8);

    // weight prep (q/k/v slices of the fused [3072][1024] buffer)
    k_tconv<<<dim3(32, 32), tb, 0, stream>>>(Wq, wqkv_t,                   D, D);
    k_tconv<<<dim3(32, 32), tb, 0, stream>>>(Wk, wqkv_t + 1024 * 1024,     D, D);
    k_tconv<<<dim3(32, 32), tb, 0, stream>>>(Wv, wqkv_t + 2 * 1024 * 1024, D, D);
    k_tconv<<<dim3(32, 32), tb, 0, stream>>>(Wo, wo_t, D, D);
    k_tconv<<<dim3(128, 32), tb, 0, stream>>>(W1, w1_t, D, FF);
    k_tconv<<<dim3(32, 128), tb, 0, stream>>>(W2, w2_t, FF, D);

    // LN1
    k_ln<<<M, 256, 0, stream>>>(x, g1, be1, h_f, h_b);

    // fused QKV GEMM -> q_b | k_b | v_b (row-major bf16 each)
    k_gemm<false, false, false, true, true><<<dim3(24, 64), 256, 0, stream>>>(
        h_b, wqkv_t, bq, nullptr, nullptr, qkv_b, M, 3072, D, bk, bv);

    // per-head V transpose (coalesced)
    k_vtrans<<<dim3(16, 16, 8), 256, 0, stream>>>(v_b, vt_b);

    // MFMA flash attention -> ctx bf16
    k_attn_mfma<<<2048, 256, 0, stream>>>(q_b, k_b, vt_b, ctx_b);

    // Wo + residual(h)
    k_gemm<false, true, true, false><<<dim3(8, 64), 256, 0, stream>>>(ctx_b, wo_t, bo, h_f, hres, nullptr, M, D, D);

    // LN2 (in-place fp32 + bf16)
    k_ln<<<M, 256, 0, stream>>>(hres, g2, be2, hres, h2_b);

    // FFN1 + exact GELU
    k_gemm<true, false, false, true><<<dim3(32, 64), 256, 0, stream>>>(h2_b, w1_t, b1, nullptr, nullptr, g_b, M, FF, D);

    // FFN2 + residual(h2)
    k_gemm<false, true, true, false><<<dim3(8, 64), 256, 0, stream>>>(g_b, w2_t, b2, hres, out, nullptr, M, D, FF);
}

// Round 5
// 906.599 us; speedup vs baseline: 1.4559x; 1.3963x over previous
//
#include <hip/hip_runtime.h>
#include <hip/hip_bf16.h>

// ---------------- common helpers ----------------
typedef unsigned short u16;
typedef __attribute__((ext_vector_type(8))) short bf16x8;
typedef __attribute__((ext_vector_type(4))) float floatx4;

__device__ __forceinline__ u16 f2b(float f) {
    union { float f; unsigned int u; } a; a.f = f;
    unsigned int u = a.u;
    unsigned int r = (u + 0x7fffu + ((u >> 16) & 1u)) >> 16; // RNE bf16
    return (u16)r;
}
__device__ __forceinline__ float b2f(u16 v) {
    union { unsigned int u; float f; } a; a.u = ((unsigned int)v) << 16;
    return a.f;
}

// async global->LDS, 16B per lane (global_load_lds_dwordx4)
__device__ __forceinline__ void gload_lds16(const void* g, void* l) {
    auto gp = (const __attribute__((address_space(1))) unsigned int*)g;
    auto lp = (__attribute__((address_space(3))) unsigned int*)l;
    __builtin_amdgcn_global_load_lds(gp, lp, 16, 0, 0);
}

// ---------------- LayerNorm (ddof=1), bf16 out ----------------
__global__ __launch_bounds__(256) void k_ln_bf(const float* __restrict__ x,
                                               const float* __restrict__ g,
                                               const float* __restrict__ be,
                                               u16* __restrict__ yb) {
    const int row = blockIdx.x;
    const int t = threadIdx.x;
    const float4 xv = ((const float4*)(x + (size_t)row * 1024))[t];
    float s  = xv.x + xv.y + xv.z + xv.w;
    float ss = xv.x * xv.x + xv.y * xv.y + xv.z * xv.z + xv.w * xv.w;
    for (int m = 1; m < 64; m <<= 1) {
        s  += __shfl_xor(s, m);
        ss += __shfl_xor(ss, m);
    }
    __shared__ float sm[8];
    const int wave = t >> 6, lane = t & 63;
    if (lane == 0) { sm[wave] = s; sm[4 + wave] = ss; }
    __syncthreads();
    s  = sm[0] + sm[1] + sm[2] + sm[3];
    ss = sm[4] + sm[5] + sm[6] + sm[7];
    const float mean = s * (1.0f / 1024.0f);
    const float var  = (ss - 1024.0f * mean * mean) * (1.0f / 1023.0f); // ddof=1
    const float rstd = rsqrtf(var + 1e-5f);
    const float4 gv = ((const float4*)g)[t];
    const float4 bv = ((const float4*)be)[t];
    float4 y;
    y.x = (xv.x - mean) * rstd * gv.x + bv.x;
    y.y = (xv.y - mean) * rstd * gv.y + bv.y;
    y.z = (xv.z - mean) * rstd * gv.z + bv.z;
    y.w = (xv.w - mean) * rstd * gv.w + bv.w;
    uint2 pk;
    pk.x = (unsigned int)f2b(y.x) | ((unsigned int)f2b(y.y) << 16);
    pk.y = (unsigned int)f2b(y.z) | ((unsigned int)f2b(y.w) << 16);
    *(uint2*)(yb + (size_t)row * 1024 + t * 4) = pk;
}

// ---------------- weight transpose + convert: W(KxN) fp32 -> Wt(NxK) bf16 ----------------
__global__ __launch_bounds__(256) void k_tconv(const float* __restrict__ W,
                                               u16* __restrict__ Wt,
                                               int K, int N) {
    __shared__ float tile[32][33];
    const int n0 = blockIdx.x * 32, k0 = blockIdx.y * 32;
    const int tx = threadIdx.x, ty = threadIdx.y; // 32 x 8
    for (int i = 0; i < 4; i++) {
        const int kr = ty + i * 8;
        tile[kr][tx] = W[(size_t)(k0 + kr) * N + n0 + tx];
    }
    __syncthreads();
    for (int i = 0; i < 4; i++) {
        const int nr = ty + i * 8;
        Wt[(size_t)(n0 + nr) * K + k0 + tx] = f2b(tile[tx][nr]);
    }
}

// batched version for the four 1024x1024 weights (z selects)
__global__ __launch_bounds__(256) void k_tconv4(const float* __restrict__ s0, u16* __restrict__ d0,
                                                const float* __restrict__ s1, u16* __restrict__ d1,
                                                const float* __restrict__ s2, u16* __restrict__ d2,
                                                const float* __restrict__ s3, u16* __restrict__ d3) {
    __shared__ float tile[32][33];
    const float* W; u16* Wt;
    switch (blockIdx.z) {
        case 0: W = s0; Wt = d0; break;
        case 1: W = s1; Wt = d1; break;
        case 2: W = s2; Wt = d2; break;
        default: W = s3; Wt = d3; break;
    }
    const int n0 = blockIdx.x * 32, k0 = blockIdx.y * 32;
    const int tx = threadIdx.x, ty = threadIdx.y;
    for (int i = 0; i < 4; i++) {
        const int kr = ty + i * 8;
        tile[kr][tx] = W[(size_t)(k0 + kr) * 1024 + n0 + tx];
    }
    __syncthreads();
    for (int i = 0; i < 4; i++) {
        const int nr = ty + i * 8;
        Wt[(size_t)(n0 + nr) * 1024 + k0 + tx] = f2b(tile[tx][nr]);
    }
}

// ---------------- per-head V transpose: v[b*T][D] -> vt[b][h][d][t] (bf16) ----------------
__global__ __launch_bounds__(256) void k_vtrans(const u16* __restrict__ v,
                                                u16* __restrict__ vt) {
    __shared__ u16 tile[64][80];
    const int t = threadIdx.x;
    const int t0 = blockIdx.x * 64, hh = blockIdx.y, bb = blockIdx.z;
    const int r = t >> 2, c0 = (t & 3) * 16;
    const u16* src = v + ((size_t)(bb * 1024 + t0 + r)) * 1024 + hh * 64 + c0;
    *(uint4*)&tile[r][c0]     = *(const uint4*)src;
    *(uint4*)&tile[r][c0 + 8] = *(const uint4*)(src + 8);
    __syncthreads();
    const int d = t >> 2;
    u16* dst = vt + (((size_t)(bb * 16 + hh) * 64 + d)) * 1024 + t0 + c0;
    union { u16 s[8]; uint4 v4; } pk;
    for (int j = 0; j < 8; j++) pk.s[j] = tile[c0 + j][d];
    *(uint4*)dst = pk.v4;
    for (int j = 0; j < 8; j++) pk.s[j] = tile[c0 + 8 + j][d];
    *(uint4*)(dst + 8) = pk.v4;
}

// ---------------- bf16 MFMA GEMM: C = A(MxK) @ Bt(NxK)^T + bias ----------------
// 128x128 tile, BK=64 (32KB LDS), 256 threads, 4 waves x (4x4 frags of 16x16x32).
// LDS rows are 8 x 16B chunks, XOR-swizzled by (row&7) applied to the *global*
// source chunk (global_load_lds dst is base+lane*16, so swizzle must be on src).
// QKV: N=3072 fused; cols [0,1024)->q, [1024,2048)->k, [2048,3072)->v; bias per section.
// RESID: bf16 residual added in epilogue.
template <bool GELU, bool RESID, bool WF32, bool WBF16, bool QKV = false>
__global__ __launch_bounds__(256) void k_gemm(const u16* __restrict__ A,
                                              const u16* __restrict__ Bt,
                                              const float* __restrict__ bias,
                                              const u16* __restrict__ residB,
                                              float* __restrict__ outF,
                                              u16* __restrict__ outB,
                                              int M, int N, int K,
                                              const float* __restrict__ bias2 = nullptr,
                                              const float* __restrict__ bias3 = nullptr) {
    __shared__ u16 As[128 * 64];
    __shared__ u16 Bs[128 * 64];
    const int t = threadIdx.x;
    const int m0 = blockIdx.y * 128, n0 = blockIdx.x * 128;
    const int lane = t & 63, wave = t >> 6;
    const int wm = (wave >> 1) * 64, wn = (wave & 1) * 64;
    const int r16 = lane & 15, quad = lane >> 4;

    floatx4 acc[4][4];
    const floatx4 zero = {0.0f, 0.0f, 0.0f, 0.0f};
    for (int i = 0; i < 4; i++)
        for (int j = 0; j < 4; j++) acc[i][j] = zero;

    // staging: 128 rows x 128B = 1024 chunks of 16B; 4 chunks/thread per matrix.
    // LDS chunk L (row=L>>3, col=L&7) holds global chunk (row, col ^ (row&7)).
    const u16* pa[4];
    const u16* pb[4];
    #pragma unroll
    for (int i = 0; i < 4; i++) {
        const int L = t + i * 256;
        const int row = L >> 3, col = L & 7;
        const int gcol = col ^ (row & 7);
        pa[i] = A  + (size_t)(m0 + row) * K + gcol * 8;
        pb[i] = Bt + (size_t)(n0 + row) * K + gcol * 8;
    }

    for (int kk = 0; kk < K; kk += 64) {
        #pragma unroll
        for (int i = 0; i < 4; i++) {
            gload_lds16(pa[i] + kk, As + (t + i * 256) * 8);
            gload_lds16(pb[i] + kk, Bs + (t + i * 256) * 8);
        }
        __syncthreads();

        #pragma unroll
        for (int ks = 0; ks < 2; ks++) {
            bf16x8 af[4], bfr[4];
            #pragma unroll
            for (int i = 0; i < 4; i++) {
                const int ra = wm + i * 16 + r16;
                af[i] = *(const bf16x8*)(As + ra * 64 + (((ks << 2) + quad) ^ (ra & 7)) * 8);
                const int rb = wn + i * 16 + r16;
                bfr[i] = *(const bf16x8*)(Bs + rb * 64 + (((ks << 2) + quad) ^ (rb & 7)) * 8);
            }
            #pragma unroll
            for (int mi = 0; mi < 4; mi++)
                #pragma unroll
                for (int ni = 0; ni < 4; ni++)
                    acc[mi][ni] = __builtin_amdgcn_mfma_f32_16x16x32_bf16(af[mi], bfr[ni], acc[mi][ni], 0, 0, 0);
        }
        __syncthreads();
    }

    // epilogue: C/D layout col = lane&15, row = quad*4 + reg
    const int sect = QKV ? (n0 >> 10) : 0;
    const float* bp = QKV ? (sect == 0 ? bias : (sect == 1 ? bias2 : bias3)) : bias;
    u16* outQ = QKV ? (outB + (size_t)sect * (8192ull * 1024ull)) : outB;
    for (int mi = 0; mi < 4; mi++)
        for (int ni = 0; ni < 4; ni++) {
            const int gcol = n0 + wn + ni * 16 + r16;
            const int coln = QKV ? (gcol & 1023) : gcol;
            const float bv = bp[coln];
            for (int r = 0; r < 4; r++) {
                const int grow = m0 + wm + mi * 16 + quad * 4 + r;
                float v = acc[mi][ni][r] + bv;
                if (GELU) v = 0.5f * v * (1.0f + erff(v * 0.70710678118654752f));
                if (QKV) {
                    outQ[(size_t)grow * 1024 + coln] = f2b(v);
                } else {
                    const size_t o = (size_t)grow * N + gcol;
                    if (RESID) v += b2f(residB[o]);
                    if (WF32) outF[o] = v;
                    if (WBF16) outB[o] = f2b(v);
                }
            }
        }
}

// ---------------- bf16 MFMA flash attention ----------------
// grid: B*H*(T/64)=2048 blocks x 256 threads; block = one (b,h), 64 q rows.
__global__ __launch_bounds__(256) void k_attn_mfma(const u16* __restrict__ q,
                                                   const u16* __restrict__ k,
                                                   const u16* __restrict__ vt,
                                                   u16* __restrict__ ctx) {
    __shared__ u16 Qs[2][64][32];
    __shared__ u16 Ks[2][64][32];
    __shared__ u16 Vs[2][64][32];
    __shared__ u16 Ps[2][64][32];
    const int t = threadIdx.x;
    const int lane = t & 63, wave = t >> 6;
    const int r16 = lane & 15, quad = lane >> 4;
    const int wq = wave * 16;
    const int bx = blockIdx.x;
    const int qt = bx & 15, hh = (bx >> 4) & 15, bb = bx >> 8;
    const size_t qk_base = ((size_t)bb * 1024) * 1024 + hh * 64;
    const size_t vt_base = ((size_t)(bb * 16 + hh) * 64) * 1024;
    const int q0 = qt * 64;

    const int srow = t >> 2, ch = t & 3;
    const int pnl = ch >> 1, soff = (ch & 1) * 16;
    {
        const u16* gp = q + qk_base + (size_t)(q0 + srow) * 1024 + ch * 16;
        *(uint4*)&Qs[pnl][srow][soff]     = *(const uint4*)gp;
        *(uint4*)&Qs[pnl][srow][soff + 8] = *(const uint4*)(gp + 8);
    }

    float m_i[4], l_i[4];
    floatx4 acc_o[4];
    const floatx4 zero = {0.0f, 0.0f, 0.0f, 0.0f};
    for (int r = 0; r < 4; r++) { m_i[r] = -INFINITY; l_i[r] = 0.0f; }
    for (int ni = 0; ni < 4; ni++) acc_o[ni] = zero;

    for (int st = 0; st < 16; st++) {
        __syncthreads();
        const int s0 = st * 64;
        {
            const u16* gk = k + qk_base + (size_t)(s0 + srow) * 1024 + ch * 16;
            *(uint4*)&Ks[pnl][srow][soff]     = *(const uint4*)gk;
            *(uint4*)&Ks[pnl][srow][soff + 8] = *(const uint4*)(gk + 8);
            const u16* gv = vt + vt_base + (size_t)srow * 1024 + s0 + ch * 16;
            *(uint4*)&Vs[pnl][srow][soff]     = *(const uint4*)gv;
            *(uint4*)&Vs[pnl][srow][soff + 8] = *(const uint4*)(gv + 8);
        }
        __syncthreads();

        floatx4 accs[4];
        for (int ni = 0; ni < 4; ni++) accs[ni] = zero;
        for (int ks = 0; ks < 2; ks++) {
            const bf16x8 af = *(const bf16x8*)&Qs[ks][wq + r16][quad * 8];
            for (int ni = 0; ni < 4; ni++) {
                const bf16x8 bf = *(const bf16x8*)&Ks[ks][ni * 16 + r16][quad * 8];
                accs[ni] = __builtin_amdgcn_mfma_f32_16x16x32_bf16(af, bf, accs[ni], 0, 0, 0);
            }
        }

        for (int r = 0; r < 4; r++) {
            float sv[4];
            float mx = -INFINITY;
            for (int ni = 0; ni < 4; ni++) {
                sv[ni] = accs[ni][r] * 0.125f;
                mx = fmaxf(mx, sv[ni]);
            }
            for (int m = 1; m < 16; m <<= 1) mx = fmaxf(mx, __shfl_xor(mx, m));
            const float mn = fmaxf(m_i[r], mx);
            const float al = __expf(m_i[r] - mn);
            float ps = 0.0f;
            u16 pb[4];
            for (int ni = 0; ni < 4; ni++) {
                const float p = __expf(sv[ni] - mn);
                ps += p;
                pb[ni] = f2b(p);
            }
            for (int m = 1; m < 16; m <<= 1) ps += __shfl_xor(ps, m);
            l_i[r] = l_i[r] * al + ps;
            m_i[r] = mn;
            for (int ni = 0; ni < 4; ni++) acc_o[ni][r] *= al;
            const int prow = wq + quad * 4 + r;
            for (int ni = 0; ni < 4; ni++)
                Ps[ni >> 1][prow][(ni & 1) * 16 + r16] = pb[ni];
        }
        // P written & read by the same wave -> no barrier needed

        for (int ks = 0; ks < 2; ks++) {
            const bf16x8 af = *(const bf16x8*)&Ps[ks][wq + r16][quad * 8];
            for (int ni = 0; ni < 4; ni++) {
                const bf16x8 bf = *(const bf16x8*)&Vs[ks][ni * 16 + r16][quad * 8];
                acc_o[ni] = __builtin_amdgcn_mfma_f32_16x16x32_bf16(af, bf, acc_o[ni], 0, 0, 0);
            }
        }
    }

    for (int r = 0; r < 4; r++) {
        const float inv = 1.0f / l_i[r];
        const size_t rowoff = qk_base + (size_t)(q0 + wq + quad * 4 + r) * 1024;
        for (int ni = 0; ni < 4; ni++)
            ctx[rowoff + ni * 16 + r16] = f2b(acc_o[ni][r] * inv);
    }
}

// ---------------- launcher ----------------
extern "C" void kernel_launch(void* const* d_in, const int* in_sizes, int n_in,
                              void* d_out, int out_size, void* d_ws, size_t ws_size,
                              hipStream_t stream) {
    const float* x   = (const float*)d_in[0];
    const float* Wq  = (const float*)d_in[1];
    const float* bq  = (const float*)d_in[2];
    const float* Wk  = (const float*)d_in[3];
    const float* bk  = (const float*)d_in[4];
    const float* Wv  = (const float*)d_in[5];
    const float* bv  = (const float*)d_in[6];
    const float* Wo  = (const float*)d_in[7];
    const float* bo  = (const float*)d_in[8];
    const float* W1  = (const float*)d_in[9];
    const float* b1  = (const float*)d_in[10];
    const float* W2  = (const float*)d_in[11];
    const float* b2  = (const float*)d_in[12];
    const float* g1  = (const float*)d_in[13];
    const float* be1 = (const float*)d_in[14];
    const float* g2  = (const float*)d_in[15];
    const float* be2 = (const float*)d_in[16];
    float* out = (float*)d_out;

    const size_t MB = 1ull << 20;
    char* ws = (char*)d_ws;
    // layout (184 MB):
    u16*   h_b    = (u16*)(ws + 0);            // 16MB bf16 h (residual for Wo)
    u16*   qkv_b  = (u16*)(ws + 16 * MB);      // 48MB: q|k|v each [8192][1024]
    u16*   q_b    = qkv_b;
    u16*   k_b    = (u16*)(ws + 32 * MB);
    u16*   v_b    = (u16*)(ws + 48 * MB);
    u16*   vt_b   = (u16*)(ws + 64 * MB);      // 16MB per-head transposed V
    u16*   ctx_b  = (u16*)(ws + 80 * MB);      // 16MB
    float* hres   = (float*)(ws + 96 * MB);    // 32MB fp32 (Wo out, LN2 in)
    u16*   h2_b   = (u16*)(ws + 128 * MB);     // 16MB
    u16*   g_b    = (u16*)(ws + 16 * MB);      // 64MB gelu acts (reuses qkv+vt, dead after attn/Wo)
    u16*   wqkv_t = (u16*)(ws + 160 * MB);     // 6MB [3072][1024]
    u16*   wo_t   = (u16*)(ws + 166 * MB);     // 2MB
    u16*   w1_t   = (u16*)(ws + 168 * MB);     // 8MB
    u16*   w2_t   = (u16*)(ws + 176 * MB);     // 8MB -> 184MB
    const int M = 8192, D = 1024, FF = 4096;
    const dim3 tb(32, 8);

    // weight prep: 4 square weights in one launch + W1 + W2
    k_tconv4<<<dim3(32, 32, 4), tb, 0, stream>>>(Wq, wqkv_t,
                                                 Wk, wqkv_t + 1024 * 1024,
                                                 Wv, wqkv_t + 2 * 1024 * 1024,
                                                 Wo, wo_t);
    k_tconv<<<dim3(128, 32), tb, 0, stream>>>(W1, w1_t, D, FF);
    k_tconv<<<dim3(32, 128), tb, 0, stream>>>(W2, w2_t, FF, D);

    // LN1 -> h_b (bf16)
    k_ln_bf<<<M, 256, 0, stream>>>(x, g1, be1, h_b);

    // fused QKV GEMM -> q|k|v
    k_gemm<false, false, false, true, true><<<dim3(24, 64), 256, 0, stream>>>(
        h_b, wqkv_t, bq, nullptr, nullptr, qkv_b, M, 3072, D, bk, bv);

    // per-head V transpose
    k_vtrans<<<dim3(16, 16, 8), 256, 0, stream>>>(v_b, vt_b);

    // MFMA flash attention -> ctx
    k_attn_mfma<<<2048, 256, 0, stream>>>(q_b, k_b, vt_b, ctx_b);

    // Wo + residual(h_b bf16) -> hres fp32
    k_gemm<false, true, true, false><<<dim3(8, 64), 256, 0, stream>>>(
        ctx_b, wo_t, bo, h_b, hres, nullptr, M, D, D);

    // LN2 -> h2_b (bf16)
    k_ln_bf<<<M, 256, 0, stream>>>(hres, g2, be2, h2_b);

    // FFN1 + exact GELU -> g_b (bf16)
    k_gemm<true, false, false, true><<<dim3(32, 64), 256, 0, stream>>>(
        h2_b, w1_t, b1, nullptr, nullptr, g_b, M, FF, D);

    // FFN2 + residual(h2_b bf16) -> out fp32
    k_gemm<false, true, true, false><<<dim3(8, 64), 256, 0, stream>>>(
        g_b, w2_t, b2, h2_b, out, nullptr, M, D, FF);
}

// Round 6
// 608.939 us; speedup vs baseline: 2.1675x; 1.4888x over previous
//
#include <hip/hip_runtime.h>
#include <hip/hip_bf16.h>

// ---------------- common helpers ----------------
typedef unsigned short u16;
typedef __attribute__((ext_vector_type(8))) short bf16x8;
typedef __attribute__((ext_vector_type(4))) float floatx4;

__device__ __forceinline__ u16 f2b(float f) {
    union { float f; unsigned int u; } a; a.f = f;
    unsigned int u = a.u;
    unsigned int r = (u + 0x7fffu + ((u >> 16) & 1u)) >> 16; // RNE bf16
    return (u16)r;
}
__device__ __forceinline__ float b2f(u16 v) {
    union { unsigned int u; float f; } a; a.u = ((unsigned int)v) << 16;
    return a.f;
}

// async global->LDS, 16B per lane (global_load_lds_dwordx4)
__device__ __forceinline__ void gload_lds16(const void* g, void* l) {
    auto gp = (const __attribute__((address_space(1))) unsigned int*)g;
    auto lp = (__attribute__((address_space(3))) unsigned int*)l;
    __builtin_amdgcn_global_load_lds(gp, lp, 16, 0, 0);
}

// ---------------- LayerNorm (ddof=1), bf16 out ----------------
__global__ __launch_bounds__(256) void k_ln_bf(const float* __restrict__ x,
                                               const float* __restrict__ g,
                                               const float* __restrict__ be,
                                               u16* __restrict__ yb) {
    const int row = blockIdx.x;
    const int t = threadIdx.x;
    const float4 xv = ((const float4*)(x + (size_t)row * 1024))[t];
    float s  = xv.x + xv.y + xv.z + xv.w;
    float ss = xv.x * xv.x + xv.y * xv.y + xv.z * xv.z + xv.w * xv.w;
    for (int m = 1; m < 64; m <<= 1) {
        s  += __shfl_xor(s, m);
        ss += __shfl_xor(ss, m);
    }
    __shared__ float sm[8];
    const int wave = t >> 6, lane = t & 63;
    if (lane == 0) { sm[wave] = s; sm[4 + wave] = ss; }
    __syncthreads();
    s  = sm[0] + sm[1] + sm[2] + sm[3];
    ss = sm[4] + sm[5] + sm[6] + sm[7];
    const float mean = s * (1.0f / 1024.0f);
    const float var  = (ss - 1024.0f * mean * mean) * (1.0f / 1023.0f); // ddof=1
    const float rstd = rsqrtf(var + 1e-5f);
    const float4 gv = ((const float4*)g)[t];
    const float4 bv = ((const float4*)be)[t];
    float4 y;
    y.x = (xv.x - mean) * rstd * gv.x + bv.x;
    y.y = (xv.y - mean) * rstd * gv.y + bv.y;
    y.z = (xv.z - mean) * rstd * gv.z + bv.z;
    y.w = (xv.w - mean) * rstd * gv.w + bv.w;
    uint2 pk;
    pk.x = (unsigned int)f2b(y.x) | ((unsigned int)f2b(y.y) << 16);
    pk.y = (unsigned int)f2b(y.z) | ((unsigned int)f2b(y.w) << 16);
    *(uint2*)(yb + (size_t)row * 1024 + t * 4) = pk;
}

// ---------------- weight transpose + convert: W(KxN) fp32 -> Wt(NxK) bf16 ----------------
__global__ __launch_bounds__(256) void k_tconv(const float* __restrict__ W,
                                               u16* __restrict__ Wt,
                                               int K, int N) {
    __shared__ float tile[32][33];
    const int n0 = blockIdx.x * 32, k0 = blockIdx.y * 32;
    const int tx = threadIdx.x, ty = threadIdx.y; // 32 x 8
    for (int i = 0; i < 4; i++) {
        const int kr = ty + i * 8;
        tile[kr][tx] = W[(size_t)(k0 + kr) * N + n0 + tx];
    }
    __syncthreads();
    for (int i = 0; i < 4; i++) {
        const int nr = ty + i * 8;
        Wt[(size_t)(n0 + nr) * K + k0 + tx] = f2b(tile[tx][nr]);
    }
}

// batched version for the four 1024x1024 weights (z selects)
__global__ __launch_bounds__(256) void k_tconv4(const float* __restrict__ s0, u16* __restrict__ d0,
                                                const float* __restrict__ s1, u16* __restrict__ d1,
                                                const float* __restrict__ s2, u16* __restrict__ d2,
                                                const float* __restrict__ s3, u16* __restrict__ d3) {
    __shared__ float tile[32][33];
    const float* W; u16* Wt;
    switch (blockIdx.z) {
        case 0: W = s0; Wt = d0; break;
        case 1: W = s1; Wt = d1; break;
        case 2: W = s2; Wt = d2; break;
        default: W = s3; Wt = d3; break;
    }
    const int n0 = blockIdx.x * 32, k0 = blockIdx.y * 32;
    const int tx = threadIdx.x, ty = threadIdx.y;
    for (int i = 0; i < 4; i++) {
        const int kr = ty + i * 8;
        tile[kr][tx] = W[(size_t)(k0 + kr) * 1024 + n0 + tx];
    }
    __syncthreads();
    for (int i = 0; i < 4; i++) {
        const int nr = ty + i * 8;
        Wt[(size_t)(n0 + nr) * 1024 + k0 + tx] = f2b(tile[tx][nr]);
    }
}

// ---------------- per-head V transpose: v[b*T][D] -> vt[b][h][d][t] (bf16) ----------------
__global__ __launch_bounds__(256) void k_vtrans(const u16* __restrict__ v,
                                                u16* __restrict__ vt) {
    __shared__ u16 tile[64][80];
    const int t = threadIdx.x;
    const int t0 = blockIdx.x * 64, hh = blockIdx.y, bb = blockIdx.z;
    const int r = t >> 2, c0 = (t & 3) * 16;
    const u16* src = v + ((size_t)(bb * 1024 + t0 + r)) * 1024 + hh * 64 + c0;
    *(uint4*)&tile[r][c0]     = *(const uint4*)src;
    *(uint4*)&tile[r][c0 + 8] = *(const uint4*)(src + 8);
    __syncthreads();
    const int d = t >> 2;
    u16* dst = vt + (((size_t)(bb * 16 + hh) * 64 + d)) * 1024 + t0 + c0;
    union { u16 s[8]; uint4 v4; } pk;
    for (int j = 0; j < 8; j++) pk.s[j] = tile[c0 + j][d];
    *(uint4*)dst = pk.v4;
    for (int j = 0; j < 8; j++) pk.s[j] = tile[c0 + 8 + j][d];
    *(uint4*)(dst + 8) = pk.v4;
}

// ---------------- bf16 MFMA GEMM: C = A(MxK) @ Bt(NxK)^T + bias ----------------
// 128x128 tile, BK=64, 256 threads, 4 waves x (4x4 frags of 16x16x32).
// L2-aware block swizzle: groups of 8 m-tiles span all n-tiles (gridDim.y % 8 == 0).
// XOR-swizzled LDS staging (swizzle applied to global source chunk).
// WBF16 outputs go through an LDS repack -> coalesced 16B stores.
template <bool GELU, bool RESID, bool WF32, bool WBF16, bool QKV = false>
__global__ __launch_bounds__(256) void k_gemm(const u16* __restrict__ A,
                                              const u16* __restrict__ Bt,
                                              const float* __restrict__ bias,
                                              const u16* __restrict__ residB,
                                              float* __restrict__ outF,
                                              u16* __restrict__ outB,
                                              int M, int N, int K,
                                              const float* __restrict__ bias2 = nullptr,
                                              const float* __restrict__ bias3 = nullptr) {
    __shared__ __align__(16) u16 S[16896]; // As(8192) | Bs(8192); epilogue: 128x132 ctile
    u16* As = S;
    u16* Bs = S + 8192;
    const int t = threadIdx.x;

    // group-m swizzle
    const int nb = gridDim.x;
    const int linear = blockIdx.y * nb + blockIdx.x;
    const int per = nb * 8;
    const int gg = linear / per, rr = linear % per;
    const int m0 = (gg * 8 + (rr & 7)) * 128;
    const int n0 = (rr >> 3) * 128;

    const int lane = t & 63, wave = t >> 6;
    const int wm = (wave >> 1) * 64, wn = (wave & 1) * 64;
    const int r16 = lane & 15, quad = lane >> 4;

    floatx4 acc[4][4];
    const floatx4 zero = {0.0f, 0.0f, 0.0f, 0.0f};
    for (int i = 0; i < 4; i++)
        for (int j = 0; j < 4; j++) acc[i][j] = zero;

    // staging: 128 rows x 128B = 1024 chunks of 16B; 4 chunks/thread per matrix.
    // LDS chunk L (row=L>>3, col=L&7) holds global chunk (row, col ^ (row&7)).
    const u16* pa[4];
    const u16* pb[4];
    #pragma unroll
    for (int i = 0; i < 4; i++) {
        const int L = t + i * 256;
        const int row = L >> 3, col = L & 7;
        const int gcol = col ^ (row & 7);
        pa[i] = A  + (size_t)(m0 + row) * K + gcol * 8;
        pb[i] = Bt + (size_t)(n0 + row) * K + gcol * 8;
    }

    for (int kk = 0; kk < K; kk += 64) {
        #pragma unroll
        for (int i = 0; i < 4; i++) {
            gload_lds16(pa[i] + kk, As + (t + i * 256) * 8);
            gload_lds16(pb[i] + kk, Bs + (t + i * 256) * 8);
        }
        __syncthreads();

        #pragma unroll
        for (int ks = 0; ks < 2; ks++) {
            bf16x8 af[4], bfr[4];
            #pragma unroll
            for (int i = 0; i < 4; i++) {
                const int ra = wm + i * 16 + r16;
                af[i] = *(const bf16x8*)(As + ra * 64 + (((ks << 2) + quad) ^ (ra & 7)) * 8);
                const int rb = wn + i * 16 + r16;
                bfr[i] = *(const bf16x8*)(Bs + rb * 64 + (((ks << 2) + quad) ^ (rb & 7)) * 8);
            }
            #pragma unroll
            for (int mi = 0; mi < 4; mi++)
                #pragma unroll
                for (int ni = 0; ni < 4; ni++)
                    acc[mi][ni] = __builtin_amdgcn_mfma_f32_16x16x32_bf16(af[mi], bfr[ni], acc[mi][ni], 0, 0, 0);
        }
        __syncthreads();
    }

    // epilogue: C/D layout col = lane&15, row = quad*4 + reg
    const int sect = QKV ? (n0 >> 10) : 0;
    const float* bp = QKV ? (sect == 0 ? bias : (sect == 1 ? bias2 : bias3)) : bias;
    u16* outQ = QKV ? (outB + (size_t)sect * (8192ull * 1024ull)) : outB;

    if (WBF16) {
        // repack through LDS (row stride 132 u16 -> conflict-free quad writes)
        u16 (*ct)[132] = (u16(*)[132])S;
        for (int mi = 0; mi < 4; mi++)
            for (int ni = 0; ni < 4; ni++) {
                const int col = wn + ni * 16 + r16;
                const int coln = QKV ? ((n0 + col) & 1023) : (n0 + col);
                const float bv = bp[coln];
                for (int r = 0; r < 4; r++) {
                    const int row = wm + mi * 16 + quad * 4 + r;
                    float v = acc[mi][ni][r] + bv;
                    if (GELU) v = 0.5f * v * (1.0f + erff(v * 0.70710678118654752f));
                    ct[row][col] = f2b(v);
                }
            }
        __syncthreads();
        const int orow = t >> 1, oc = (t & 1) * 64;
        const int grow = m0 + orow;
        u16* dst = QKV ? (outQ + (size_t)grow * 1024 + ((n0 + oc) & 1023))
                       : (outB + (size_t)grow * N + n0 + oc);
        #pragma unroll
        for (int j = 0; j < 8; j++)
            *(uint4*)(dst + j * 8) = *(const uint4*)&ct[orow][oc + j * 8];
    } else {
        for (int mi = 0; mi < 4; mi++)
            for (int ni = 0; ni < 4; ni++) {
                const int gcol = n0 + wn + ni * 16 + r16;
                const float bv = bias[gcol];
                for (int r = 0; r < 4; r++) {
                    const int grow = m0 + wm + mi * 16 + quad * 4 + r;
                    float v = acc[mi][ni][r] + bv;
                    if (GELU) v = 0.5f * v * (1.0f + erff(v * 0.70710678118654752f));
                    const size_t o = (size_t)grow * N + gcol;
                    if (RESID) v += b2f(residB[o]);
                    if (WF32) outF[o] = v;
                }
            }
    }
}

// ---------------- bf16 MFMA flash attention ----------------
// grid: B*H*(T/64)=2048 blocks x 256 threads; block = one (b,h), 64 q rows.
__global__ __launch_bounds__(256) void k_attn_mfma(const u16* __restrict__ q,
                                                   const u16* __restrict__ k,
                                                   const u16* __restrict__ vt,
                                                   u16* __restrict__ ctx) {
    __shared__ u16 Qs[2][64][32];
    __shared__ u16 Ks[2][64][32];
    __shared__ u16 Vs[2][64][32];
    __shared__ u16 Ps[2][64][32];
    const int t = threadIdx.x;
    const int lane = t & 63, wave = t >> 6;
    const int r16 = lane & 15, quad = lane >> 4;
    const int wq = wave * 16;
    const int bx = blockIdx.x;
    const int qt = bx & 15, hh = (bx >> 4) & 15, bb = bx >> 8;
    const size_t qk_base = ((size_t)bb * 1024) * 1024 + hh * 64;
    const size_t vt_base = ((size_t)(bb * 16 + hh) * 64) * 1024;
    const int q0 = qt * 64;

    const int srow = t >> 2, ch = t & 3;
    const int pnl = ch >> 1, soff = (ch & 1) * 16;
    {
        const u16* gp = q + qk_base + (size_t)(q0 + srow) * 1024 + ch * 16;
        *(uint4*)&Qs[pnl][srow][soff]     = *(const uint4*)gp;
        *(uint4*)&Qs[pnl][srow][soff + 8] = *(const uint4*)(gp + 8);
    }

    float m_i[4], l_i[4];
    floatx4 acc_o[4];
    const floatx4 zero = {0.0f, 0.0f, 0.0f, 0.0f};
    for (int r = 0; r < 4; r++) { m_i[r] = -INFINITY; l_i[r] = 0.0f; }
    for (int ni = 0; ni < 4; ni++) acc_o[ni] = zero;

    for (int st = 0; st < 16; st++) {
        __syncthreads();
        const int s0 = st * 64;
        {
            const u16* gk = k + qk_base + (size_t)(s0 + srow) * 1024 + ch * 16;
            *(uint4*)&Ks[pnl][srow][soff]     = *(const uint4*)gk;
            *(uint4*)&Ks[pnl][srow][soff + 8] = *(const uint4*)(gk + 8);
            const u16* gv = vt + vt_base + (size_t)srow * 1024 + s0 + ch * 16;
            *(uint4*)&Vs[pnl][srow][soff]     = *(const uint4*)gv;
            *(uint4*)&Vs[pnl][srow][soff + 8] = *(const uint4*)(gv + 8);
        }
        __syncthreads();

        floatx4 accs[4];
        for (int ni = 0; ni < 4; ni++) accs[ni] = zero;
        for (int ks = 0; ks < 2; ks++) {
            const bf16x8 af = *(const bf16x8*)&Qs[ks][wq + r16][quad * 8];
            for (int ni = 0; ni < 4; ni++) {
                const bf16x8 bf = *(const bf16x8*)&Ks[ks][ni * 16 + r16][quad * 8];
                accs[ni] = __builtin_amdgcn_mfma_f32_16x16x32_bf16(af, bf, accs[ni], 0, 0, 0);
            }
        }

        for (int r = 0; r < 4; r++) {
            float sv[4];
            float mx = -INFINITY;
            for (int ni = 0; ni < 4; ni++) {
                sv[ni] = accs[ni][r] * 0.125f;
                mx = fmaxf(mx, sv[ni]);
            }
            for (int m = 1; m < 16; m <<= 1) mx = fmaxf(mx, __shfl_xor(mx, m));
            const float mn = fmaxf(m_i[r], mx);
            const float al = __expf(m_i[r] - mn);
            float ps = 0.0f;
            u16 pb[4];
            for (int ni = 0; ni < 4; ni++) {
                const float p = __expf(sv[ni] - mn);
                ps += p;
                pb[ni] = f2b(p);
            }
            for (int m = 1; m < 16; m <<= 1) ps += __shfl_xor(ps, m);
            l_i[r] = l_i[r] * al + ps;
            m_i[r] = mn;
            for (int ni = 0; ni < 4; ni++) acc_o[ni][r] *= al;
            const int prow = wq + quad * 4 + r;
            for (int ni = 0; ni < 4; ni++)
                Ps[ni >> 1][prow][(ni & 1) * 16 + r16] = pb[ni];
        }
        // P written & read by the same wave -> no barrier needed

        for (int ks = 0; ks < 2; ks++) {
            const bf16x8 af = *(const bf16x8*)&Ps[ks][wq + r16][quad * 8];
            for (int ni = 0; ni < 4; ni++) {
                const bf16x8 bf = *(const bf16x8*)&Vs[ks][ni * 16 + r16][quad * 8];
                acc_o[ni] = __builtin_amdgcn_mfma_f32_16x16x32_bf16(af, bf, acc_o[ni], 0, 0, 0);
            }
        }
    }

    for (int r = 0; r < 4; r++) {
        const float inv = 1.0f / l_i[r];
        const size_t rowoff = qk_base + (size_t)(q0 + wq + quad * 4 + r) * 1024;
        for (int ni = 0; ni < 4; ni++)
            ctx[rowoff + ni * 16 + r16] = f2b(acc_o[ni][r] * inv);
    }
}

// ---------------- launcher ----------------
extern "C" void kernel_launch(void* const* d_in, const int* in_sizes, int n_in,
                              void* d_out, int out_size, void* d_ws, size_t ws_size,
                              hipStream_t stream) {
    const float* x   = (const float*)d_in[0];
    const float* Wq  = (const float*)d_in[1];
    const float* bq  = (const float*)d_in[2];
    const float* Wk  = (const float*)d_in[3];
    const float* bk  = (const float*)d_in[4];
    const float* Wv  = (const float*)d_in[5];
    const float* bv  = (const float*)d_in[6];
    const float* Wo  = (const float*)d_in[7];
    const float* bo  = (const float*)d_in[8];
    const float* W1  = (const float*)d_in[9];
    const float* b1  = (const float*)d_in[10];
    const float* W2  = (const float*)d_in[11];
    const float* b2  = (const float*)d_in[12];
    const float* g1  = (const float*)d_in[13];
    const float* be1 = (const float*)d_in[14];
    const float* g2  = (const float*)d_in[15];
    const float* be2 = (const float*)d_in[16];
    float* out = (float*)d_out;

    const size_t MB = 1ull << 20;
    char* ws = (char*)d_ws;
    // layout (184 MB):
    u16*   h_b    = (u16*)(ws + 0);            // 16MB bf16 h (residual for Wo)
    u16*   qkv_b  = (u16*)(ws + 16 * MB);      // 48MB: q|k|v each [8192][1024]
    u16*   q_b    = qkv_b;
    u16*   k_b    = (u16*)(ws + 32 * MB);
    u16*   v_b    = (u16*)(ws + 48 * MB);
    u16*   vt_b   = (u16*)(ws + 64 * MB);      // 16MB per-head transposed V
    u16*   ctx_b  = (u16*)(ws + 80 * MB);      // 16MB
    float* hres   = (float*)(ws + 96 * MB);    // 32MB fp32 (Wo out, LN2 in)
    u16*   h2_b   = (u16*)(ws + 128 * MB);     // 16MB
    u16*   g_b    = (u16*)(ws + 16 * MB);      // 64MB gelu acts (reuses qkv+vt)
    u16*   wqkv_t = (u16*)(ws + 160 * MB);     // 6MB [3072][1024]
    u16*   wo_t   = (u16*)(ws + 166 * MB);     // 2MB
    u16*   w1_t   = (u16*)(ws + 168 * MB);     // 8MB
    u16*   w2_t   = (u16*)(ws + 176 * MB);     // 8MB -> 184MB
    const int M = 8192, D = 1024, FF = 4096;
    const dim3 tb(32, 8);

    // weight prep
    k_tconv4<<<dim3(32, 32, 4), tb, 0, stream>>>(Wq, wqkv_t,
                                                 Wk, wqkv_t + 1024 * 1024,
                                                 Wv, wqkv_t + 2 * 1024 * 1024,
                                                 Wo, wo_t);
    k_tconv<<<dim3(128, 32), tb, 0, stream>>>(W1, w1_t, D, FF);
    k_tconv<<<dim3(32, 128), tb, 0, stream>>>(W2, w2_t, FF, D);

    // LN1 -> h_b (bf16)
    k_ln_bf<<<M, 256, 0, stream>>>(x, g1, be1, h_b);

    // fused QKV GEMM -> q|k|v
    k_gemm<false, false, false, true, true><<<dim3(24, 64), 256, 0, stream>>>(
        h_b, wqkv_t, bq, nullptr, nullptr, qkv_b, M, 3072, D, bk, bv);

    // per-head V transpose
    k_vtrans<<<dim3(16, 16, 8), 256, 0, stream>>>(v_b, vt_b);

    // MFMA flash attention -> ctx
    k_attn_mfma<<<2048, 256, 0, stream>>>(q_b, k_b, vt_b, ctx_b);

    // Wo + residual(h_b bf16) -> hres fp32
    k_gemm<false, true, true, false><<<dim3(8, 64), 256, 0, stream>>>(
        ctx_b, wo_t, bo, h_b, hres, nullptr, M, D, D);

    // LN2 -> h2_b (bf16)
    k_ln_bf<<<M, 256, 0, stream>>>(hres, g2, be2, h2_b);

    // FFN1 + exact GELU -> g_b (bf16)
    k_gemm<true, false, false, true><<<dim3(32, 64), 256, 0, stream>>>(
        h2_b, w1_t, b1, nullptr, nullptr, g_b, M, FF, D);

    // FFN2 + residual(h2_b bf16) -> out fp32
    k_gemm<false, true, true, false><<<dim3(8, 64), 256, 0, stream>>>(
        g_b, w2_t, b2, h2_b, out, nullptr, M, D, FF);
}